// Round 3
// baseline (166.400 us; speedup 1.0000x reference)
//
#include <hip/hip_runtime.h>

// Quantized 3x3 conv, stride 1, pad 1 (pad value = input zero point 3).
// x: int32 [32][128][56][56] (values in int8 range)
// weight: int32 [256][128][3][3]
// bias: int32 [256]
// weight_scale: float [256]
// out: int32 [32][256][56][56] (quantized int8 values in int32 container)

#define NB    32
#define CIN   128
#define HH    56
#define WW    56
#define COUT  256
#define HP    58          // padded H
#define WP    58          // padded W
#define PIX   (HH*WW)     // 3136
#define KTOT  1152        // 9 * 128
#define NCHUNK 18         // K chunks of 64

typedef int v4i __attribute__((ext_vector_type(4)));

// ---------------- Phase 1a: pack x (NCHW int32 -> padded NHWC int8) -------
// xp8[nl][hp][wp][ci] for nl in [0, nc), global batch = n0 + nl. Pad = ZP 3.
__global__ void pack_x_kernel(const int* __restrict__ x,
                              unsigned char* __restrict__ xp8,
                              int n0) {
    int nl = blockIdx.x / HP;      // local batch index within chunk
    int hp = blockIdx.x % HP;
    int nb = n0 + nl;              // global batch
    int t  = threadIdx.x;          // 256
    int cig = t & 31;              // group of 4 ci
    int wg  = t >> 5;              // 0..7
    bool hin = (hp >= 1 && hp <= HH);
    int h = hp - 1;
    for (int wp = wg; wp < WP; wp += 8) {
        unsigned int pack;
        if (hin && wp >= 1 && wp <= WW) {
            int w = wp - 1;
            const int* xb = x + (((nb*CIN + cig*4)*HH + h)*WW + w);
            const int s = HH*WW;
            int v0 = xb[0], v1 = xb[s], v2 = xb[2*s], v3 = xb[3*s];
            pack = (v0 & 0xFF) | ((v1 & 0xFF) << 8) |
                   ((v2 & 0xFF) << 16) | ((unsigned)(v3 & 0xFF) << 24);
        } else {
            pack = 0x03030303u;    // IN_ZP replicated
        }
        *(unsigned int*)(xp8 + ((size_t)((nl*HP + hp)*WP + wp) * CIN) + cig*4) = pack;
    }
}

// ---------------- Phase 1b: pack weight -> w8[co][k], k = r*128 + ci ------
__global__ void pack_w_kernel(const int* __restrict__ wt,
                              unsigned char* __restrict__ w8) {
    int co = blockIdx.x;           // 256
    int t  = threadIdx.x;          // 128; 288 dwords per row
    for (int idx = t; idx < KTOT/4; idx += 128) {
        int k  = idx * 4;
        int r  = k >> 7;           // tap index 0..8 (fixed within the dword)
        int ci = k & 127;
        const int* wb = wt + ((co*CIN + ci)*9 + r);
        int v0 = wb[0], v1 = wb[9], v2 = wb[18], v3 = wb[27];
        unsigned int pack = (v0 & 0xFF) | ((v1 & 0xFF) << 8) |
                            ((v2 & 0xFF) << 16) | ((unsigned)(v3 & 0xFF) << 24);
        *(unsigned int*)(w8 + (size_t)co*KTOT + k) = pack;
    }
}

// ---------------- Phase 2: implicit GEMM with i8 MFMA ---------------------
// Grid: 49 pixel-tiles * nc batches. Block: 256 threads = 4 waves.
// Wave wm computes co in [wm*64, wm*64+64) x 64 pixels.
__launch_bounds__(256)
__global__ void conv_kernel(const unsigned char* __restrict__ w8,
                            const unsigned char* __restrict__ xp8,
                            const int* __restrict__ bias,
                            const float* __restrict__ wscale,
                            int* __restrict__ out,
                            int n0) {
    int bx = blockIdx.x;
    int pt = bx % 49;
    int nl = bx / 49;              // local batch in chunk
    int nb = n0 + nl;              // global batch
    int p0 = pt * 64;

    int tid  = threadIdx.x;
    int lane = tid & 63;
    int wm   = tid >> 6;           // 0..3
    int lr   = lane & 15;
    int lg   = lane >> 4;

    const unsigned char* aptr[4];
#pragma unroll
    for (int i = 0; i < 4; ++i) {
        int co = wm*64 + i*16 + lr;
        aptr[i] = w8 + (size_t)co*KTOT + lg*16;
    }
    const unsigned char* bptr[4];
#pragma unroll
    for (int j = 0; j < 4; ++j) {
        int p = p0 + j*16 + lr;
        int h = p / WW, w = p % WW;
        bptr[j] = xp8 + ((size_t)((nl*HP + h)*WP + w))*CIN + lg*16;
    }

    v4i acc[4][4];
#pragma unroll
    for (int i = 0; i < 4; ++i)
#pragma unroll
        for (int j = 0; j < 4; ++j)
            acc[i][j] = (v4i){0, 0, 0, 0};

#pragma unroll
    for (int t = 0; t < NCHUNK; ++t) {
        int r   = t >> 1;
        int kh  = r / 3, kw = r % 3;
        int ci0 = (t & 1) << 6;
        int koff = (kh*WP + kw)*CIN + ci0;   // uniform per chunk
        int aoff = t * 64;

        v4i a[4], b[4];
#pragma unroll
        for (int i = 0; i < 4; ++i) a[i] = *(const v4i*)(aptr[i] + aoff);
#pragma unroll
        for (int j = 0; j < 4; ++j) b[j] = *(const v4i*)(bptr[j] + koff);

#pragma unroll
        for (int i = 0; i < 4; ++i)
#pragma unroll
            for (int j = 0; j < 4; ++j)
                acc[i][j] = __builtin_amdgcn_mfma_i32_16x16x64_i8(a[i], b[j], acc[i][j], 0, 0, 0);
    }

    // Epilogue: q = clamp(rint((acc+bias) * (0.05*ws/0.1) + (-2)), -128, 127)
#pragma unroll
    for (int i = 0; i < 4; ++i) {
#pragma unroll
        for (int rr = 0; rr < 4; ++rr) {
            int co = wm*64 + i*16 + lg*4 + rr;
            float sc = __fdiv_rn(__fmul_rn(0.05f, wscale[co]), 0.1f);
            int bs = bias[co];
            int* orow = out + ((size_t)(nb*COUT + co))*PIX + p0;
#pragma unroll
            for (int j = 0; j < 4; ++j) {
                float accf = (float)(acc[i][j][rr] + bs);
                float y = __fadd_rn(__fmul_rn(accf, sc), -2.0f);
                y = rintf(y);
                y = fminf(fmaxf(y, -128.0f), 127.0f);
                orow[j*16 + lr] = (int)y;
            }
        }
    }
}

// ---------------- Fallback: naive direct conv (only if ws too small) ------
__launch_bounds__(256)
__global__ void conv_direct_kernel(const int* __restrict__ x,
                                   const int* __restrict__ wt,
                                   const int* __restrict__ bias,
                                   const float* __restrict__ wscale,
                                   int* __restrict__ out) {
    size_t idx = (size_t)blockIdx.x * 256 + threadIdx.x;
    if (idx >= (size_t)NB * COUT * PIX) return;
    int w  = idx % WW;
    int h  = (idx / WW) % HH;
    int co = (idx / PIX) % COUT;
    int nb = idx / ((size_t)PIX * COUT);
    int acc = 0;
    for (int ci = 0; ci < CIN; ++ci) {
        const int* xb = x + ((size_t)(nb*CIN + ci)*HH)*WW;
        const int* wb = wt + ((size_t)(co*CIN + ci)*9);
        for (int kh = 0; kh < 3; ++kh) {
            int hh = h + kh - 1;
            for (int kw = 0; kw < 3; ++kw) {
                int ww2 = w + kw - 1;
                int xv = (hh >= 0 && hh < HH && ww2 >= 0 && ww2 < WW)
                         ? xb[hh*WW + ww2] : 3;
                acc += xv * wb[kh*3 + kw];
            }
        }
    }
    float sc = __fdiv_rn(__fmul_rn(0.05f, wscale[co]), 0.1f);
    float y = __fadd_rn(__fmul_rn((float)(acc + bias[co]), sc), -2.0f);
    y = rintf(y);
    y = fminf(fmaxf(y, -128.0f), 127.0f);
    out[idx] = (int)y;
}

extern "C" void kernel_launch(void* const* d_in, const int* in_sizes, int n_in,
                              void* d_out, int out_size, void* d_ws, size_t ws_size,
                              hipStream_t stream) {
    const int*   x      = (const int*)d_in[0];
    const int*   weight = (const int*)d_in[1];
    const int*   bias   = (const int*)d_in[2];
    const float* wscale = (const float*)d_in[3];
    int*         out    = (int*)d_out;

    const size_t XOFF = 320u << 10;                  // w8 region: 288KB used
    const size_t BPB  = (size_t)HP * WP * CIN;       // 430,592 B per batch

    // Largest power-of-two batch chunk that fits the workspace.
    int nchk = 0;
    if (ws_size >= XOFF + BPB) {
        size_t navail = (ws_size - XOFF) / BPB;
        nchk = navail >= 32 ? 32 : navail >= 16 ? 16 : navail >= 8 ? 8
             : navail >= 4 ? 4 : navail >= 2 ? 2 : 1;
    }

    if (nchk == 0) {
        // Workspace too small for even one batch: naive direct conv.
        size_t total = (size_t)NB * COUT * PIX;
        conv_direct_kernel<<<dim3((total + 255) / 256), dim3(256), 0, stream>>>(
            x, weight, bias, wscale, out);
        return;
    }

    unsigned char* ws  = (unsigned char*)d_ws;
    unsigned char* w8  = ws;                          // 294,912 B
    unsigned char* xp8 = ws + XOFF;                   // nchk * 430,592 B

    pack_w_kernel<<<dim3(COUT), dim3(128), 0, stream>>>(weight, w8);
    for (int n0 = 0; n0 < NB; n0 += nchk) {
        int nc = (NB - n0 < nchk) ? (NB - n0) : nchk;
        pack_x_kernel<<<dim3(nc*HP), dim3(256), 0, stream>>>(x, xp8, n0);
        conv_kernel<<<dim3(49*nc), dim3(256), 0, stream>>>(w8, xp8, bias, wscale, out, n0);
    }
}

// Round 4
// 98.649 us; speedup vs baseline: 1.6868x; 1.6868x over previous
//
#include <hip/hip_runtime.h>

// Quantized 3x3 conv, stride 1, pad 1 (pad value = input zero point 3).
// x: int32 [32][128][56][56] (values in int8 range)
// weight: int32 [256][128][3][3]
// bias: int32 [256]
// weight_scale: float [256]
// out: int32 [32][256][56][56] (quantized int8 values in int32 container)

#define NB    32
#define CIN   128
#define HH    56
#define WW    56
#define COUT  256
#define HP    58          // padded H
#define WP    58          // padded W
#define PIX   (HH*WW)     // 3136
#define KTOT  1152        // 9 * 128
#define NCHUNK 18         // K chunks of 64

#define ABYTES 16384      // A chunk in LDS: 256 rows x 64 B
#define BBYTES 4096       // B chunk in LDS: 64 rows x 64 B
#define BUFB   (ABYTES + BBYTES)   // 20480 per buffer, x2 double-buffered

typedef int v4i __attribute__((ext_vector_type(4)));

#define GLOAD_LDS(gsrc, ldst) \
    __builtin_amdgcn_global_load_lds( \
        (const __attribute__((address_space(1))) void*)(gsrc), \
        (__attribute__((address_space(3))) void*)(ldst), 16, 0, 0)

// ---------------- Phase 1a: pack x (NCHW int32 -> padded NHWC int8) -------
__global__ void pack_x_kernel(const int* __restrict__ x,
                              unsigned char* __restrict__ xp8,
                              int n0) {
    int nl = blockIdx.x / HP;
    int hp = blockIdx.x % HP;
    int nb = n0 + nl;
    int t  = threadIdx.x;          // 256
    int cig = t & 31;
    int wg  = t >> 5;
    bool hin = (hp >= 1 && hp <= HH);
    int h = hp - 1;
    for (int wp = wg; wp < WP; wp += 8) {
        unsigned int pack;
        if (hin && wp >= 1 && wp <= WW) {
            int w = wp - 1;
            const int* xb = x + (((nb*CIN + cig*4)*HH + h)*WW + w);
            const int s = HH*WW;
            int v0 = xb[0], v1 = xb[s], v2 = xb[2*s], v3 = xb[3*s];
            pack = (v0 & 0xFF) | ((v1 & 0xFF) << 8) |
                   ((v2 & 0xFF) << 16) | ((unsigned)(v3 & 0xFF) << 24);
        } else {
            pack = 0x03030303u;    // IN_ZP replicated
        }
        *(unsigned int*)(xp8 + ((size_t)((nl*HP + hp)*WP + wp) * CIN) + cig*4) = pack;
    }
}

// ---------------- Phase 1b: pack weight -> w8[co][k], k = r*128 + ci ------
__global__ void pack_w_kernel(const int* __restrict__ wt,
                              unsigned char* __restrict__ w8) {
    int co = blockIdx.x;
    int t  = threadIdx.x;          // 128
    for (int idx = t; idx < KTOT/4; idx += 128) {
        int k  = idx * 4;
        int r  = k >> 7;
        int ci = k & 127;
        const int* wb = wt + ((co*CIN + ci)*9 + r);
        int v0 = wb[0], v1 = wb[9], v2 = wb[18], v3 = wb[27];
        unsigned int pack = (v0 & 0xFF) | ((v1 & 0xFF) << 8) |
                            ((v2 & 0xFF) << 16) | ((unsigned)(v3 & 0xFF) << 24);
        *(unsigned int*)(w8 + (size_t)co*KTOT + k) = pack;
    }
}

__device__ __forceinline__ int koff_of(int t) {
    int r  = t >> 1;
    int kh = (r >= 6) ? 2 : (r >= 3 ? 1 : 0);
    int kw = r - kh*3;
    return ((kh*WP + kw) << 7) + ((t & 1) << 6);
}

// ---------------- Phase 2: LDS-staged double-buffered implicit GEMM -------
// Grid: 49 pixel-tiles * nc batches. Block: 256 threads = 4 waves.
// Per K-chunk (64 B of K): stage A (256x64B) + B (64x64B) into LDS via
// global_load_lds w16, double-buffered; XOR slot-swizzle (s ^ ((row>>1)&3))
// applied on the global SOURCE (linear LDS dest) and on the ds_read address.
__launch_bounds__(256)
__global__ void conv_kernel(const unsigned char* __restrict__ w8,
                            const unsigned char* __restrict__ xp8,
                            const int* __restrict__ bias,
                            const float* __restrict__ wscale,
                            int* __restrict__ out,
                            int n0) {
    __shared__ __align__(16) unsigned char lds[2*BUFB];

    int bx = blockIdx.x;
    int pt = bx % 49;
    int nl = bx / 49;
    int nb = n0 + nl;
    int p0 = pt * 64;

    int tid  = threadIdx.x;
    int lane = tid & 63;
    int wm   = tid >> 6;           // 0..3
    int lr   = lane & 15;
    int lg   = lane >> 4;
    int wmu  = __builtin_amdgcn_readfirstlane(wm);

    // ---- staging source addresses (per lane) ----
    int l4 = lane >> 2;                              // 0..15 (row within 16-row group)
    int sw = (lane & 3) ^ ((lane >> 3) & 3);         // swizzled data k-slot
    const unsigned char* asrc[4];
#pragma unroll
    for (int kk = 0; kk < 4; ++kk) {
        int r = wm*64 + kk*16 + l4;                  // co row 0..255
        asrc[kk] = w8 + (size_t)r*KTOT + sw*16;      // + t*64 at stage time
    }
    {
        // keep pixel base for B staging
    }
    int prow = wm*16 + l4;                           // 0..63
    int p  = p0 + prow;
    int ph = p / WW, pw = p % WW;
    const unsigned char* bsrc = xp8 + ((size_t)((nl*HP + ph)*WP + pw))*CIN + sw*16;

    // ---- fragment read addresses in LDS (swizzled) ----
    int rslot = lg ^ ((lr >> 1) & 3);
    int va = wm*4096 + lr*64 + rslot*16;             // a[i] at va + i*1024
    int vb = ABYTES  + lr*64 + rslot*16;             // b[j] at vb + j*1024

    v4i acc[4][4];
#pragma unroll
    for (int i = 0; i < 4; ++i)
#pragma unroll
        for (int j = 0; j < 4; ++j)
            acc[i][j] = (v4i){0, 0, 0, 0};

#define STAGE(T, BUFOFF) do {                                                  \
        int koff_ = koff_of(T);                                                \
        _Pragma("unroll")                                                      \
        for (int kk_ = 0; kk_ < 4; ++kk_)                                      \
            GLOAD_LDS(asrc[kk_] + (T)*64,                                      \
                      &lds[(BUFOFF) + wmu*4096 + kk_*1024]);                   \
        GLOAD_LDS(bsrc + koff_, &lds[(BUFOFF) + ABYTES + wmu*1024]);           \
    } while (0)

#define BODY(BUFOFF) do {                                                      \
        v4i a_[4], b_[4];                                                      \
        _Pragma("unroll")                                                      \
        for (int i_ = 0; i_ < 4; ++i_)                                         \
            a_[i_] = *(const v4i*)&lds[(BUFOFF) + va + i_*1024];               \
        _Pragma("unroll")                                                      \
        for (int j_ = 0; j_ < 4; ++j_)                                         \
            b_[j_] = *(const v4i*)&lds[(BUFOFF) + vb + j_*1024];               \
        _Pragma("unroll")                                                      \
        for (int i_ = 0; i_ < 4; ++i_)                                         \
            _Pragma("unroll")                                                  \
            for (int j_ = 0; j_ < 4; ++j_)                                     \
                acc[i_][j_] = __builtin_amdgcn_mfma_i32_16x16x64_i8(           \
                    a_[i_], b_[j_], acc[i_][j_], 0, 0, 0);                     \
    } while (0)

    // prologue: stage chunk 0 into buf0
    STAGE(0, 0);
    __syncthreads();

    for (int tt = 0; tt < 9; ++tt) {
        int t0 = 2*tt;
        STAGE(t0 + 1, BUFB);       // prefetch odd chunk into buf1
        BODY(0);                   // compute even chunk from buf0
        __syncthreads();
        if (tt < 8) STAGE(t0 + 2, 0);  // prefetch next even chunk into buf0
        BODY(BUFB);                // compute odd chunk from buf1
        __syncthreads();
    }
#undef STAGE
#undef BODY

    // Epilogue: q = clamp(rint((acc+bias) * (0.05*ws/0.1) + (-2)), -128, 127)
#pragma unroll
    for (int i = 0; i < 4; ++i) {
#pragma unroll
        for (int rr = 0; rr < 4; ++rr) {
            int co = wm*64 + i*16 + lg*4 + rr;
            float sc = __fdiv_rn(__fmul_rn(0.05f, wscale[co]), 0.1f);
            int bs = bias[co];
            int* orow = out + ((size_t)(nb*COUT + co))*PIX + p0;
#pragma unroll
            for (int j = 0; j < 4; ++j) {
                float accf = (float)(acc[i][j][rr] + bs);
                float y = __fadd_rn(__fmul_rn(accf, sc), -2.0f);
                y = rintf(y);
                y = fminf(fmaxf(y, -128.0f), 127.0f);
                orow[j*16 + lr] = (int)y;
            }
        }
    }
}

// ---------------- Fallback: naive direct conv (only if ws too small) ------
__launch_bounds__(256)
__global__ void conv_direct_kernel(const int* __restrict__ x,
                                   const int* __restrict__ wt,
                                   const int* __restrict__ bias,
                                   const float* __restrict__ wscale,
                                   int* __restrict__ out) {
    size_t idx = (size_t)blockIdx.x * 256 + threadIdx.x;
    if (idx >= (size_t)NB * COUT * PIX) return;
    int w  = idx % WW;
    int h  = (idx / WW) % HH;
    int co = (idx / PIX) % COUT;
    int nb = idx / ((size_t)PIX * COUT);
    int acc = 0;
    for (int ci = 0; ci < CIN; ++ci) {
        const int* xb = x + ((size_t)(nb*CIN + ci)*HH)*WW;
        const int* wb = wt + ((size_t)(co*CIN + ci)*9);
        for (int kh = 0; kh < 3; ++kh) {
            int hh = h + kh - 1;
            for (int kw = 0; kw < 3; ++kw) {
                int ww2 = w + kw - 1;
                int xv = (hh >= 0 && hh < HH && ww2 >= 0 && ww2 < WW)
                         ? xb[hh*WW + ww2] : 3;
                acc += xv * wb[kh*3 + kw];
            }
        }
    }
    float sc = __fdiv_rn(__fmul_rn(0.05f, wscale[co]), 0.1f);
    float y = __fadd_rn(__fmul_rn((float)(acc + bias[co]), sc), -2.0f);
    y = rintf(y);
    y = fminf(fmaxf(y, -128.0f), 127.0f);
    out[idx] = (int)y;
}

extern "C" void kernel_launch(void* const* d_in, const int* in_sizes, int n_in,
                              void* d_out, int out_size, void* d_ws, size_t ws_size,
                              hipStream_t stream) {
    const int*   x      = (const int*)d_in[0];
    const int*   weight = (const int*)d_in[1];
    const int*   bias   = (const int*)d_in[2];
    const float* wscale = (const float*)d_in[3];
    int*         out    = (int*)d_out;

    const size_t XOFF = 320u << 10;                  // w8 region: 288KB used
    const size_t BPB  = (size_t)HP * WP * CIN;       // 430,592 B per batch

    int nchk = 0;
    if (ws_size >= XOFF + BPB) {
        size_t navail = (ws_size - XOFF) / BPB;
        nchk = navail >= 32 ? 32 : navail >= 16 ? 16 : navail >= 8 ? 8
             : navail >= 4 ? 4 : navail >= 2 ? 2 : 1;
    }

    if (nchk == 0) {
        size_t total = (size_t)NB * COUT * PIX;
        conv_direct_kernel<<<dim3((total + 255) / 256), dim3(256), 0, stream>>>(
            x, weight, bias, wscale, out);
        return;
    }

    unsigned char* ws  = (unsigned char*)d_ws;
    unsigned char* w8  = ws;
    unsigned char* xp8 = ws + XOFF;

    pack_w_kernel<<<dim3(COUT), dim3(128), 0, stream>>>(weight, w8);
    for (int n0 = 0; n0 < NB; n0 += nchk) {
        int nc = (NB - n0 < nchk) ? (NB - n0) : nchk;
        pack_x_kernel<<<dim3(nc*HP), dim3(256), 0, stream>>>(x, xp8, n0);
        conv_kernel<<<dim3(49*nc), dim3(256), 0, stream>>>(w8, xp8, bias, wscale, out, n0);
    }
}

// Round 5
// 92.318 us; speedup vs baseline: 1.8025x; 1.0686x over previous
//
#include <hip/hip_runtime.h>

// Quantized 3x3 conv, stride 1, pad 1 (pad value = input zero point 3).
// x: int32 [32][128][56][56] (values in int8 range)
// weight: int32 [256][128][3][3]
// bias: int32 [256]
// weight_scale: float [256]
// out: int32 [32][256][56][56] (quantized int8 values in int32 container)

#define NB    32
#define CIN   128
#define HH    56
#define WW    56
#define COUT  256
#define HP    58          // padded H
#define WP    58          // padded W
#define PIX   (HH*WW)     // 3136
#define KTOT  1152        // 9 * 128
#define NCHUNK 18         // K chunks of 64

#define BBYTES 4096       // B chunk in LDS: 64 rows x 64 B (double-buffered)

typedef int v4i __attribute__((ext_vector_type(4)));

#define GLOAD_LDS(gsrc, ldst) \
    __builtin_amdgcn_global_load_lds( \
        (const __attribute__((address_space(1))) void*)(gsrc), \
        (__attribute__((address_space(3))) void*)(ldst), 16, 0, 0)

// ---------------- Phase 1a: pack x interior (NCHW int32 -> NHWC int8) -----
// Border (pad = 0x03) is pre-filled by hipMemsetAsync. Reads coalesced in w.
__global__ void pack_x_kernel(const int* __restrict__ x,
                              unsigned char* __restrict__ xp8,
                              int n0) {
    int bx = blockIdx.x;
    int nl = bx / HH;
    int h  = bx % HH;
    int nb = n0 + nl;
    int tid = threadIdx.x;         // 256
    int wl  = tid & 63;            // w (0..55 active)
    int cg  = tid >> 6;            // 0..3
    if (wl >= WW) return;
    unsigned char* dst = xp8 + ((size_t)((nl*HP + h + 1)*WP + (wl + 1)))*CIN;
    const int s = HH*WW;
#pragma unroll
    for (int it = 0; it < 8; ++it) {
        int ci0 = cg*4 + it*16;
        const int* xb = x + (((size_t)(nb*CIN + ci0)*HH + h)*WW + wl);
        int v0 = xb[0], v1 = xb[s], v2 = xb[2*s], v3 = xb[3*s];
        unsigned int pack = (v0 & 0xFF) | ((v1 & 0xFF) << 8) |
                            ((v2 & 0xFF) << 16) | ((unsigned)(v3 & 0xFF) << 24);
        *(unsigned int*)(dst + ci0) = pack;
    }
}

// ---------------- Phase 1b: pack weight into FRAGMENT order ----------------
// w8f[((t*16 + g)*16 + lr)*64 + (k&63)], t=k>>6 chunk, g=co>>4, lr=co&15,
// k = r*128 + ci (tap-major). A wave's A-fragment = contiguous 1KB.
__global__ void pack_w_kernel(const int* __restrict__ wt,
                              unsigned char* __restrict__ w8f) {
    int co = blockIdx.x;           // 256
    int t  = threadIdx.x;          // 128
    for (int idx = t; idx < KTOT/4; idx += 128) {
        int k  = idx * 4;
        int r  = k >> 7;           // tap 0..8
        int ci = k & 127;
        const int* wb = wt + ((co*CIN + ci)*9 + r);
        int v0 = wb[0], v1 = wb[9], v2 = wb[18], v3 = wb[27];
        unsigned int pack = (v0 & 0xFF) | ((v1 & 0xFF) << 8) |
                            ((v2 & 0xFF) << 16) | ((unsigned)(v3 & 0xFF) << 24);
        int tch = k >> 6;
        size_t dst = ((size_t)((tch*16 + (co >> 4))*16 + (co & 15)))*64 + (k & 63);
        *(unsigned int*)(w8f + dst) = pack;
    }
}

__device__ __forceinline__ int koff_of(int t) {
    int r  = t >> 1;
    int kh = (r >= 6) ? 2 : (r >= 3 ? 1 : 0);
    int kw = r - kh*3;
    return ((kh*WP + kw) << 7) + ((t & 1) << 6);
}

// ---------------- Phase 2: implicit GEMM, A in regs, B in LDS -------------
// Grid: 49 pixel-tiles * nc batches. Block: 256 threads = 4 waves.
// A: fragment-ordered w8f, coalesced 1KB global loads, reg double-buffered.
// B: 64px x 64B staged via global_load_lds w16, LDS double-buffered,
//    XOR slot-swizzle (slot ^ ((row>>1)&3)) on source + read (0 conflicts).
__launch_bounds__(256)
__global__ void conv_kernel(const unsigned char* __restrict__ w8f,
                            const unsigned char* __restrict__ xp8,
                            const int* __restrict__ bias,
                            const float* __restrict__ wscale,
                            int* __restrict__ out,
                            int n0) {
    __shared__ __align__(16) unsigned char ldsB[2*BBYTES];

    int bx = blockIdx.x;
    int pt = bx % 49;
    int nl = bx / 49;
    int nb = n0 + nl;
    int p0 = pt * 64;

    int tid  = threadIdx.x;
    int lane = tid & 63;
    int wm   = tid >> 6;           // 0..3
    int lr   = lane & 15;
    int lg   = lane >> 4;
    int wmu  = __builtin_amdgcn_readfirstlane(wm);

    // ---- B staging source (per lane), swizzled k-slot ----
    int l4 = lane >> 2;                              // row within 16-row group
    int sw = (lane & 3) ^ ((lane >> 3) & 3);         // swizzled data k-slot
    int prow = wm*16 + l4;                           // 0..63
    int p  = p0 + prow;
    int ph = p / WW, pw = p % WW;
    const unsigned char* bsrc = xp8 + ((size_t)((nl*HP + ph)*WP + pw))*CIN + sw*16;

    // ---- B fragment read address (swizzled) ----
    int rslot = lg ^ ((lr >> 1) & 3);
    int vb = lr*64 + rslot*16;                       // b[j] at vb + j*1024

    // ---- A fragment base: contiguous 1KB per (chunk, frag) ----
    const unsigned char* abase = w8f + (size_t)(wm*4)*1024 + (lr*64 + lg*16);

    v4i acc[4][4];
#pragma unroll
    for (int i = 0; i < 4; ++i)
#pragma unroll
        for (int j = 0; j < 4; ++j)
            acc[i][j] = (v4i){0, 0, 0, 0};

#define STAGE_B(T, BUFOFF) \
    GLOAD_LDS(bsrc + koff_of(T), &ldsB[(BUFOFF) + wmu*1024])

    v4i a_cur[4], a_nxt[4];
#pragma unroll
    for (int i = 0; i < 4; ++i) a_cur[i] = *(const v4i*)(abase + i*1024);
    STAGE_B(0, 0);
    __syncthreads();

#pragma unroll
    for (int t = 0; t < NCHUNK; ++t) {
        if (t < NCHUNK-1) {
#pragma unroll
            for (int i = 0; i < 4; ++i)
                a_nxt[i] = *(const v4i*)(abase + (size_t)(t+1)*16384 + i*1024);
            STAGE_B(t+1, ((t+1)&1)*BBYTES);
        }
        v4i b_[4];
#pragma unroll
        for (int j = 0; j < 4; ++j)
            b_[j] = *(const v4i*)&ldsB[(t&1)*BBYTES + vb + j*1024];
#pragma unroll
        for (int i = 0; i < 4; ++i)
#pragma unroll
            for (int j = 0; j < 4; ++j)
                acc[i][j] = __builtin_amdgcn_mfma_i32_16x16x64_i8(
                    a_cur[i], b_[j], acc[i][j], 0, 0, 0);
        __syncthreads();
        if (t < NCHUNK-1) {
#pragma unroll
            for (int i = 0; i < 4; ++i) a_cur[i] = a_nxt[i];
        }
    }
#undef STAGE_B

    // Epilogue: q = clamp(rint((acc+bias) * (0.05*ws/0.1) + (-2)), -128, 127)
#pragma unroll
    for (int i = 0; i < 4; ++i) {
#pragma unroll
        for (int rr = 0; rr < 4; ++rr) {
            int co = wm*64 + i*16 + lg*4 + rr;
            float sc = __fdiv_rn(__fmul_rn(0.05f, wscale[co]), 0.1f);
            int bs = bias[co];
            int* orow = out + ((size_t)(nb*COUT + co))*PIX + p0;
#pragma unroll
            for (int j = 0; j < 4; ++j) {
                float accf = (float)(acc[i][j][rr] + bs);
                float y = __fadd_rn(__fmul_rn(accf, sc), -2.0f);
                y = rintf(y);
                y = fminf(fmaxf(y, -128.0f), 127.0f);
                orow[j*16 + lr] = (int)y;
            }
        }
    }
}

// ---------------- Fallback: naive direct conv (only if ws too small) ------
__launch_bounds__(256)
__global__ void conv_direct_kernel(const int* __restrict__ x,
                                   const int* __restrict__ wt,
                                   const int* __restrict__ bias,
                                   const float* __restrict__ wscale,
                                   int* __restrict__ out) {
    size_t idx = (size_t)blockIdx.x * 256 + threadIdx.x;
    if (idx >= (size_t)NB * COUT * PIX) return;
    int w  = idx % WW;
    int h  = (idx / WW) % HH;
    int co = (idx / PIX) % COUT;
    int nb = idx / ((size_t)PIX * COUT);
    int acc = 0;
    for (int ci = 0; ci < CIN; ++ci) {
        const int* xb = x + ((size_t)(nb*CIN + ci)*HH)*WW;
        const int* wb = wt + ((size_t)(co*CIN + ci)*9);
        for (int kh = 0; kh < 3; ++kh) {
            int hh = h + kh - 1;
            for (int kw = 0; kw < 3; ++kw) {
                int ww2 = w + kw - 1;
                int xv = (hh >= 0 && hh < HH && ww2 >= 0 && ww2 < WW)
                         ? xb[hh*WW + ww2] : 3;
                acc += xv * wb[kh*3 + kw];
            }
        }
    }
    float sc = __fdiv_rn(__fmul_rn(0.05f, wscale[co]), 0.1f);
    float y = __fadd_rn(__fmul_rn((float)(acc + bias[co]), sc), -2.0f);
    y = rintf(y);
    y = fminf(fmaxf(y, -128.0f), 127.0f);
    out[idx] = (int)y;
}

extern "C" void kernel_launch(void* const* d_in, const int* in_sizes, int n_in,
                              void* d_out, int out_size, void* d_ws, size_t ws_size,
                              hipStream_t stream) {
    const int*   x      = (const int*)d_in[0];
    const int*   weight = (const int*)d_in[1];
    const int*   bias   = (const int*)d_in[2];
    const float* wscale = (const float*)d_in[3];
    int*         out    = (int*)d_out;

    const size_t XOFF = 320u << 10;                  // w8f region: 288KB used
    const size_t BPB  = (size_t)HP * WP * CIN;       // 430,592 B per batch

    int nchk = 0;
    if (ws_size >= XOFF + BPB) {
        size_t navail = (ws_size - XOFF) / BPB;
        nchk = navail >= 32 ? 32 : navail >= 16 ? 16 : navail >= 8 ? 8
             : navail >= 4 ? 4 : navail >= 2 ? 2 : 1;
    }

    if (nchk == 0) {
        size_t total = (size_t)NB * COUT * PIX;
        conv_direct_kernel<<<dim3((total + 255) / 256), dim3(256), 0, stream>>>(
            x, weight, bias, wscale, out);
        return;
    }

    unsigned char* ws  = (unsigned char*)d_ws;
    unsigned char* w8f = ws;
    unsigned char* xp8 = ws + XOFF;

    // Pad borders (and everything else) with the input zero point once;
    // pack_x overwrites the interior each chunk iteration.
    hipMemsetAsync(xp8, 0x03, (size_t)nchk * BPB, stream);
    pack_w_kernel<<<dim3(COUT), dim3(128), 0, stream>>>(weight, w8f);
    for (int n0 = 0; n0 < NB; n0 += nchk) {
        int nc = (NB - n0 < nchk) ? (NB - n0) : nchk;
        pack_x_kernel<<<dim3(nc*HH), dim3(256), 0, stream>>>(x, xp8, n0);
        conv_kernel<<<dim3(49*nc), dim3(256), 0, stream>>>(w8f, xp8, bias, wscale, out, n0);
    }
}

// Round 6
// 80.859 us; speedup vs baseline: 2.0579x; 1.1417x over previous
//
#include <hip/hip_runtime.h>

// Quantized 3x3 conv, stride 1, pad 1 (pad value = input zero point 3).
// x: int32 [32][128][56][56] (values in int8 range)
// weight: int32 [256][128][3][3]
// bias: int32 [256]
// weight_scale: float [256]
// out: int32 [32][256][56][56] (quantized int8 values in int32 container)

#define NB    32
#define CIN   128
#define HH    56
#define WW    56
#define COUT  256
#define HP    58          // padded H
#define WP    58          // padded W
#define PIX   (HH*WW)     // 3136
#define KTOT  1152        // 9 * 128
#define NCHUNK 18         // K chunks of 64

#define BBYTES 4096       // B chunk in LDS: 64 rows x 64 B (double-buffered)

typedef int v4i __attribute__((ext_vector_type(4)));

#define GLOAD_LDS(gsrc, ldst) \
    __builtin_amdgcn_global_load_lds( \
        (const __attribute__((address_space(1))) void*)(gsrc), \
        (__attribute__((address_space(3))) void*)(ldst), 16, 0, 0)

// ---------------- Phase 1a: pack x (NCHW int32 -> padded NHWC int8) -------
// Handles borders itself (rows hp==0/57 full fill; wp==0/57 per row).
__global__ void pack_x_kernel(const int* __restrict__ x,
                              unsigned char* __restrict__ xp8,
                              int n0) {
    int bx = blockIdx.x;
    int nl = bx / HP;
    int hp = bx % HP;
    int nb = n0 + nl;
    int tid = threadIdx.x;         // 256
    unsigned char* row = xp8 + (size_t)(nl*HP + hp) * WP * CIN;
    const v4i zp = {0x03030303, 0x03030303, 0x03030303, 0x03030303};

    if (hp == 0 || hp == HP-1) {
        // full pad row: 58*128 B = 464 x 16B
        for (int i = tid; i < (WP*CIN)/16; i += 256)
            ((v4i*)row)[i] = zp;
        return;
    }
    // left/right pad columns: slots 0..7 and 456..463
    if (tid < 16) {
        int off = (tid < 8) ? tid : ((WP*CIN)/16 - 16 + tid);
        ((v4i*)row)[off] = zp;
    }
    int h  = hp - 1;
    int wl = tid & 63;             // w (0..55 active)
    int cg = tid >> 6;             // 0..3
    if (wl >= WW) return;
    unsigned char* dst = row + (size_t)(wl + 1) * CIN;
    const int s = HH*WW;
#pragma unroll
    for (int it = 0; it < 8; ++it) {
        int ci0 = cg*4 + it*16;
        const int* xb = x + (((size_t)(nb*CIN + ci0)*HH + h)*WW + wl);
        int v0 = xb[0], v1 = xb[s], v2 = xb[2*s], v3 = xb[3*s];
        unsigned int pack = (v0 & 0xFF) | ((v1 & 0xFF) << 8) |
                            ((v2 & 0xFF) << 16) | ((unsigned)(v3 & 0xFF) << 24);
        *(unsigned int*)(dst + ci0) = pack;
    }
}

// ---------------- Phase 1b: pack weight into FRAGMENT order ----------------
// w8f[((t*16 + g)*16 + lr)*64 + (k&63)], t=k>>6 chunk, g=co>>4, lr=co&15,
// k = r*128 + ci (tap-major). A wave's A-fragment = contiguous 1KB.
__global__ void pack_w_kernel(const int* __restrict__ wt,
                              unsigned char* __restrict__ w8f) {
    int co = blockIdx.x;           // 256
    int t  = threadIdx.x;          // 128
    for (int idx = t; idx < KTOT/4; idx += 128) {
        int k  = idx * 4;
        int r  = k >> 7;           // tap 0..8
        int ci = k & 127;
        const int* wb = wt + ((co*CIN + ci)*9 + r);
        int v0 = wb[0], v1 = wb[9], v2 = wb[18], v3 = wb[27];
        unsigned int pack = (v0 & 0xFF) | ((v1 & 0xFF) << 8) |
                            ((v2 & 0xFF) << 16) | ((unsigned)(v3 & 0xFF) << 24);
        int tch = k >> 6;
        size_t dst = ((size_t)((tch*16 + (co >> 4))*16 + (co & 15)))*64 + (k & 63);
        *(unsigned int*)(w8f + dst) = pack;
    }
}

__device__ __forceinline__ int koff_of(int t) {
    int r  = t >> 1;
    int kh = (r >= 6) ? 2 : (r >= 3 ? 1 : 0);
    int kw = r - kh*3;
    return ((kh*WP + kw) << 7) + ((t & 1) << 6);
}

// ---------------- Phase 2: counted-vmcnt pipelined implicit GEMM ----------
// Grid: 49 pixel-tiles * nc batches. Block: 256 threads = 4 waves.
// A: fragment-ordered w8f -> regs (coalesced 1KB loads, double-buffered).
// B: 64px x 64B via global_load_lds w16, LDS double-buffered, XOR swizzle.
// Raw s_barrier + counted s_waitcnt vmcnt(N): prefetches of chunk t+1 stay
// in flight ACROSS the barrier (T4). Per iter: 5 VMEM ops (1 stage + 4 A).
// At pre-compute barrier, ops younger than STAGE(t): A(t)x4 + STAGE(t+1) +
// A(t+1)x4 = 9 -> vmcnt(9) guarantees own B(t) landed; compiler inserts
// exact waits for the A-register uses.
__launch_bounds__(256, 3)
__global__ void conv_kernel(const unsigned char* __restrict__ w8f,
                            const unsigned char* __restrict__ xp8,
                            const int* __restrict__ bias,
                            const float* __restrict__ wscale,
                            int* __restrict__ out,
                            int n0) {
    __shared__ __align__(16) unsigned char ldsB[2*BBYTES];

    int bx = blockIdx.x;
    int pt = bx % 49;
    int nl = bx / 49;
    int nb = n0 + nl;
    int p0 = pt * 64;

    int tid  = threadIdx.x;
    int lane = tid & 63;
    int wm   = tid >> 6;           // 0..3
    int lr   = lane & 15;
    int lg   = lane >> 4;
    int wmu  = __builtin_amdgcn_readfirstlane(wm);

    // ---- B staging source (per lane), swizzled k-slot ----
    int l4 = lane >> 2;                              // row within 16-row group
    int sw = (lane & 3) ^ ((lane >> 3) & 3);         // swizzled data k-slot
    int prow = wm*16 + l4;                           // 0..63
    int p  = p0 + prow;
    int ph = p / WW, pw = p % WW;
    const unsigned char* bsrc = xp8 + ((size_t)((nl*HP + ph)*WP + pw))*CIN + sw*16;

    // ---- B fragment read address (swizzled) ----
    int rslot = lg ^ ((lr >> 1) & 3);
    int vb = lr*64 + rslot*16;                       // b[j] at vb + j*1024

    // ---- A fragment base: contiguous 1KB per (chunk, frag) ----
    const unsigned char* abase = w8f + (size_t)(wm*4)*1024 + (lr*64 + lg*16);

    v4i acc[4][4];
#pragma unroll
    for (int i = 0; i < 4; ++i)
#pragma unroll
        for (int j = 0; j < 4; ++j)
            acc[i][j] = (v4i){0, 0, 0, 0};

#define STAGE_B(T, BUFOFF) \
    GLOAD_LDS(bsrc + koff_of(T), &ldsB[(BUFOFF) + wmu*1024])

    v4i a_cur[4], a_nxt[4];
    // prologue: 1 stage + 4 A-loads in flight
    STAGE_B(0, 0);
#pragma unroll
    for (int i = 0; i < 4; ++i) a_cur[i] = *(const v4i*)(abase + i*1024);

#pragma unroll
    for (int t = 0; t < NCHUNK; ++t) {
        if (t < NCHUNK-1) {
            STAGE_B(t+1, ((t+1)&1)*BBYTES);
#pragma unroll
            for (int i = 0; i < 4; ++i)
                a_nxt[i] = *(const v4i*)(abase + (size_t)(t+1)*16384 + i*1024);
            asm volatile("s_waitcnt vmcnt(9)" ::: "memory");
        } else {
            asm volatile("s_waitcnt vmcnt(4)" ::: "memory");
        }
        __builtin_amdgcn_sched_barrier(0);
        __builtin_amdgcn_s_barrier();      // all waves' B(t) visible in LDS

        v4i b_[4];
#pragma unroll
        for (int j = 0; j < 4; ++j)
            b_[j] = *(const v4i*)&ldsB[(t&1)*BBYTES + vb + j*1024];
#pragma unroll
        for (int i = 0; i < 4; ++i)
#pragma unroll
            for (int j = 0; j < 4; ++j)
                acc[i][j] = __builtin_amdgcn_mfma_i32_16x16x64_i8(
                    a_cur[i], b_[j], acc[i][j], 0, 0, 0);

        __builtin_amdgcn_s_barrier();      // all waves done reading buf[t&1]
        if (t < NCHUNK-1) {
#pragma unroll
            for (int i = 0; i < 4; ++i) a_cur[i] = a_nxt[i];
        }
    }
#undef STAGE_B

    // Epilogue: q = clamp(rint((acc+bias) * (0.05*ws/0.1) + (-2)), -128, 127)
#pragma unroll
    for (int i = 0; i < 4; ++i) {
#pragma unroll
        for (int rr = 0; rr < 4; ++rr) {
            int co = wm*64 + i*16 + lg*4 + rr;
            float sc = __fdiv_rn(__fmul_rn(0.05f, wscale[co]), 0.1f);
            int bs = bias[co];
            int* orow = out + ((size_t)(nb*COUT + co))*PIX + p0;
#pragma unroll
            for (int j = 0; j < 4; ++j) {
                float accf = (float)(acc[i][j][rr] + bs);
                float y = __fadd_rn(__fmul_rn(accf, sc), -2.0f);
                y = rintf(y);
                y = fminf(fmaxf(y, -128.0f), 127.0f);
                orow[j*16 + lr] = (int)y;
            }
        }
    }
}

// ---------------- Fallback: naive direct conv (only if ws too small) ------
__launch_bounds__(256)
__global__ void conv_direct_kernel(const int* __restrict__ x,
                                   const int* __restrict__ wt,
                                   const int* __restrict__ bias,
                                   const float* __restrict__ wscale,
                                   int* __restrict__ out) {
    size_t idx = (size_t)blockIdx.x * 256 + threadIdx.x;
    if (idx >= (size_t)NB * COUT * PIX) return;
    int w  = idx % WW;
    int h  = (idx / WW) % HH;
    int co = (idx / PIX) % COUT;
    int nb = idx / ((size_t)PIX * COUT);
    int acc = 0;
    for (int ci = 0; ci < CIN; ++ci) {
        const int* xb = x + ((size_t)(nb*CIN + ci)*HH)*WW;
        const int* wb = wt + ((size_t)(co*CIN + ci)*9);
        for (int kh = 0; kh < 3; ++kh) {
            int hh = h + kh - 1;
            for (int kw = 0; kw < 3; ++kw) {
                int ww2 = w + kw - 1;
                int xv = (hh >= 0 && hh < HH && ww2 >= 0 && ww2 < WW)
                         ? xb[hh*WW + ww2] : 3;
                acc += xv * wb[kh*3 + kw];
            }
        }
    }
    float sc = __fdiv_rn(__fmul_rn(0.05f, wscale[co]), 0.1f);
    float y = __fadd_rn(__fmul_rn((float)(acc + bias[co]), sc), -2.0f);
    y = rintf(y);
    y = fminf(fmaxf(y, -128.0f), 127.0f);
    out[idx] = (int)y;
}

extern "C" void kernel_launch(void* const* d_in, const int* in_sizes, int n_in,
                              void* d_out, int out_size, void* d_ws, size_t ws_size,
                              hipStream_t stream) {
    const int*   x      = (const int*)d_in[0];
    const int*   weight = (const int*)d_in[1];
    const int*   bias   = (const int*)d_in[2];
    const float* wscale = (const float*)d_in[3];
    int*         out    = (int*)d_out;

    const size_t XOFF = 320u << 10;                  // w8f region: 288KB used
    const size_t BPB  = (size_t)HP * WP * CIN;       // 430,592 B per batch

    int nchk = 0;
    if (ws_size >= XOFF + BPB) {
        size_t navail = (ws_size - XOFF) / BPB;
        nchk = navail >= 32 ? 32 : navail >= 16 ? 16 : navail >= 8 ? 8
             : navail >= 4 ? 4 : navail >= 2 ? 2 : 1;
    }

    if (nchk == 0) {
        size_t total = (size_t)NB * COUT * PIX;
        conv_direct_kernel<<<dim3((total + 255) / 256), dim3(256), 0, stream>>>(
            x, weight, bias, wscale, out);
        return;
    }

    unsigned char* ws  = (unsigned char*)d_ws;
    unsigned char* w8f = ws;
    unsigned char* xp8 = ws + XOFF;

    pack_w_kernel<<<dim3(COUT), dim3(128), 0, stream>>>(weight, w8f);
    for (int n0 = 0; n0 < NB; n0 += nchk) {
        int nc = (NB - n0 < nchk) ? (NB - n0) : nchk;
        pack_x_kernel<<<dim3(nc*HP), dim3(256), 0, stream>>>(x, xp8, n0);
        conv_kernel<<<dim3(49*nc), dim3(256), 0, stream>>>(w8f, xp8, bias, wscale, out, n0);
    }
}

// Round 7
// 73.829 us; speedup vs baseline: 2.2539x; 1.0952x over previous
//
#include <hip/hip_runtime.h>

// Quantized 3x3 conv, stride 1, pad 1 (pad value = input zero point 3).
// x: int32 [32][128][56][56] (values in int8 range)
// weight: int32 [256][128][3][3]
// bias: int32 [256]
// weight_scale: float [256]
// out: int32 [32][256][56][56] (quantized int8 values in int32 container)

#define NB    32
#define CIN   128
#define HH    56
#define WW    56
#define COUT  256
#define HP    58          // padded H
#define WP    58          // padded W
#define PIX   (HH*WW)     // 3136
#define KTOT  1152        // 9 * 128
#define NCHUNK 18         // K chunks of 64

#define NPT   28          // pixel tiles per batch (3136 = 28*112)
#define BN    112         // pixels per block
#define NJ    7           // B fragments per wave (112/16)
#define BBYTES (NJ*1024)  // B chunk in LDS: 112 rows x 64 B (double-buffered)

typedef int v4i __attribute__((ext_vector_type(4)));

#define GLOAD_LDS(gsrc, ldst) \
    __builtin_amdgcn_global_load_lds( \
        (const __attribute__((address_space(1))) void*)(gsrc), \
        (__attribute__((address_space(3))) void*)(ldst), 16, 0, 0)

// ---------------- Phase 1a: pack x (NCHW int32 -> padded NHWC int8) -------
// Handles borders itself (rows hp==0/57 full fill; wp==0/57 per row).
__global__ void pack_x_kernel(const int* __restrict__ x,
                              unsigned char* __restrict__ xp8,
                              int n0) {
    int bx = blockIdx.x;
    int nl = bx / HP;
    int hp = bx % HP;
    int nb = n0 + nl;
    int tid = threadIdx.x;         // 256
    unsigned char* row = xp8 + (size_t)(nl*HP + hp) * WP * CIN;
    const v4i zp = {0x03030303, 0x03030303, 0x03030303, 0x03030303};

    if (hp == 0 || hp == HP-1) {
        for (int i = tid; i < (WP*CIN)/16; i += 256)
            ((v4i*)row)[i] = zp;
        return;
    }
    if (tid < 16) {
        int off = (tid < 8) ? tid : ((WP*CIN)/16 - 16 + tid);
        ((v4i*)row)[off] = zp;
    }
    int h  = hp - 1;
    int wl = tid & 63;             // w (0..55 active)
    int cg = tid >> 6;             // 0..3
    if (wl >= WW) return;
    unsigned char* dst = row + (size_t)(wl + 1) * CIN;
    const int s = HH*WW;
#pragma unroll
    for (int it = 0; it < 8; ++it) {
        int ci0 = cg*4 + it*16;
        const int* xb = x + (((size_t)(nb*CIN + ci0)*HH + h)*WW + wl);
        int v0 = xb[0], v1 = xb[s], v2 = xb[2*s], v3 = xb[3*s];
        unsigned int pack = (v0 & 0xFF) | ((v1 & 0xFF) << 8) |
                            ((v2 & 0xFF) << 16) | ((unsigned)(v3 & 0xFF) << 24);
        *(unsigned int*)(dst + ci0) = pack;
    }
}

// ---------------- Phase 1b: pack weight into FRAGMENT order ----------------
// w8f[((t*16 + g)*16 + lr)*64 + (k&63)], t=k>>6 chunk, g=co>>4, lr=co&15,
// k = r*128 + ci (tap-major). A wave's A-fragment = contiguous 1KB.
__global__ void pack_w_kernel(const int* __restrict__ wt,
                              unsigned char* __restrict__ w8f) {
    int co = blockIdx.x;           // 256
    int t  = threadIdx.x;          // 128
    for (int idx = t; idx < KTOT/4; idx += 128) {
        int k  = idx * 4;
        int r  = k >> 7;           // tap 0..8
        int ci = k & 127;
        const int* wb = wt + ((co*CIN + ci)*9 + r);
        int v0 = wb[0], v1 = wb[9], v2 = wb[18], v3 = wb[27];
        unsigned int pack = (v0 & 0xFF) | ((v1 & 0xFF) << 8) |
                            ((v2 & 0xFF) << 16) | ((unsigned)(v3 & 0xFF) << 24);
        int tch = k >> 6;
        size_t dst = ((size_t)((tch*16 + (co >> 4))*16 + (co & 15)))*64 + (k & 63);
        *(unsigned int*)(w8f + dst) = pack;
    }
}

__device__ __forceinline__ int koff_of(int t) {
    int r  = t >> 1;
    int kh = (r >= 6) ? 2 : (r >= 3 ? 1 : 0);
    int kw = r - kh*3;
    return ((kh*WP + kw) << 7) + ((t & 1) << 6);
}

// ---------------- Phase 2: counted-vmcnt pipelined implicit GEMM ----------
// Grid: 28 pixel-tiles * nc batches. Block: 256 threads = 4 waves.
// Tile: 256 co x 112 px. Wave wm: co in [wm*64, wm*64+64) x all 112 px.
// A: fragment-ordered w8f -> regs (coalesced 1KB loads, double-buffered).
// B: 112px x 64B via global_load_lds w16, LDS double-buffered, XOR swizzle.
// Each wave issues 2 B-stage ops (wave 3 duplicates slot 6) + 4 A loads per
// iter -> uniform counted waits: vmcnt(10) main loop, vmcnt(4) last iter.
__launch_bounds__(256, 2)
__global__ void conv_kernel(const unsigned char* __restrict__ w8f,
                            const unsigned char* __restrict__ xp8,
                            const int* __restrict__ bias,
                            const float* __restrict__ wscale,
                            int* __restrict__ out,
                            int n0) {
    __shared__ __align__(16) unsigned char ldsB[2*BBYTES];

    int bx = blockIdx.x;
    int pt = bx % NPT;
    int nl = bx / NPT;
    int nb = n0 + nl;
    int p0 = pt * BN;

    int tid  = threadIdx.x;
    int lane = tid & 63;
    int wm   = tid >> 6;           // 0..3
    int lr   = lane & 15;
    int lg   = lane >> 4;

    // ---- B staging: slots s0,s1 per wave (16 px x 64B each) ----
    int l4 = lane >> 2;                              // row within 16-row group
    int sw = (lane & 3) ^ ((lane >> 3) & 3);         // swizzled data k-slot
    int s0 = wm*2;
    int s1 = (wm*2+1 > 6) ? 6 : wm*2+1;              // wave3 duplicates slot 6
    int s0u = __builtin_amdgcn_readfirstlane(s0);
    int s1u = __builtin_amdgcn_readfirstlane(s1);
    int pA = p0 + s0*16 + l4;
    int pB = p0 + s1*16 + l4;
    const unsigned char* bsrc0 =
        xp8 + ((size_t)((nl*HP + pA/WW)*WP + pA%WW))*CIN + sw*16;
    const unsigned char* bsrc1 =
        xp8 + ((size_t)((nl*HP + pB/WW)*WP + pB%WW))*CIN + sw*16;

    // ---- B fragment read address (swizzled) ----
    int rslot = lg ^ ((lr >> 1) & 3);
    int vb = lr*64 + rslot*16;                       // b[j] at vb + j*1024

    // ---- A fragment base: contiguous 1KB per (chunk, frag) ----
    const unsigned char* abase = w8f + (size_t)(wm*4)*1024 + (lr*64 + lg*16);

    v4i acc[4][NJ];
#pragma unroll
    for (int i = 0; i < 4; ++i)
#pragma unroll
        for (int j = 0; j < NJ; ++j)
            acc[i][j] = (v4i){0, 0, 0, 0};

#define STAGE_B(T, BUFOFF) do {                                                \
        int koff_ = koff_of(T);                                                \
        GLOAD_LDS(bsrc0 + koff_, &ldsB[(BUFOFF) + s0u*1024]);                  \
        GLOAD_LDS(bsrc1 + koff_, &ldsB[(BUFOFF) + s1u*1024]);                  \
    } while (0)

    v4i a_cur[4], a_nxt[4];
    // prologue: 2 stage ops + 4 A-loads in flight
    STAGE_B(0, 0);
#pragma unroll
    for (int i = 0; i < 4; ++i) a_cur[i] = *(const v4i*)(abase + i*1024);

#pragma unroll
    for (int t = 0; t < NCHUNK; ++t) {
        if (t < NCHUNK-1) {
            STAGE_B(t+1, ((t+1)&1)*BBYTES);
#pragma unroll
            for (int i = 0; i < 4; ++i)
                a_nxt[i] = *(const v4i*)(abase + (size_t)(t+1)*16384 + i*1024);
            // younger than own B(t): A(t)x4 + B(t+1)x2 + A(t+1)x4 = 10
            asm volatile("s_waitcnt vmcnt(10)" ::: "memory");
        } else {
            asm volatile("s_waitcnt vmcnt(4)" ::: "memory");
        }
        __builtin_amdgcn_sched_barrier(0);
        __builtin_amdgcn_s_barrier();      // all waves' B(t) visible in LDS

        v4i b_[NJ];
#pragma unroll
        for (int j = 0; j < NJ; ++j)
            b_[j] = *(const v4i*)&ldsB[(t&1)*BBYTES + vb + j*1024];
#pragma unroll
        for (int i = 0; i < 4; ++i)
#pragma unroll
            for (int j = 0; j < NJ; ++j)
                acc[i][j] = __builtin_amdgcn_mfma_i32_16x16x64_i8(
                    a_cur[i], b_[j], acc[i][j], 0, 0, 0);

        __builtin_amdgcn_s_barrier();      // all waves done reading buf[t&1]
        if (t < NCHUNK-1) {
#pragma unroll
            for (int i = 0; i < 4; ++i) a_cur[i] = a_nxt[i];
        }
    }
#undef STAGE_B

    // Epilogue: q = clamp(rint((acc+bias) * (0.05*ws/0.1) + (-2)), -128, 127)
#pragma unroll
    for (int i = 0; i < 4; ++i) {
#pragma unroll
        for (int rr = 0; rr < 4; ++rr) {
            int co = wm*64 + i*16 + lg*4 + rr;
            float sc = __fdiv_rn(__fmul_rn(0.05f, wscale[co]), 0.1f);
            int bs = bias[co];
            int* orow = out + ((size_t)(nb*COUT + co))*PIX + p0;
#pragma unroll
            for (int j = 0; j < NJ; ++j) {
                float accf = (float)(acc[i][j][rr] + bs);
                float y = __fadd_rn(__fmul_rn(accf, sc), -2.0f);
                y = rintf(y);
                y = fminf(fmaxf(y, -128.0f), 127.0f);
                orow[j*16 + lr] = (int)y;
            }
        }
    }
}

// ---------------- Fallback: naive direct conv (only if ws too small) ------
__launch_bounds__(256)
__global__ void conv_direct_kernel(const int* __restrict__ x,
                                   const int* __restrict__ wt,
                                   const int* __restrict__ bias,
                                   const float* __restrict__ wscale,
                                   int* __restrict__ out) {
    size_t idx = (size_t)blockIdx.x * 256 + threadIdx.x;
    if (idx >= (size_t)NB * COUT * PIX) return;
    int w  = idx % WW;
    int h  = (idx / WW) % HH;
    int co = (idx / PIX) % COUT;
    int nb = idx / ((size_t)PIX * COUT);
    int acc = 0;
    for (int ci = 0; ci < CIN; ++ci) {
        const int* xb = x + ((size_t)(nb*CIN + ci)*HH)*WW;
        const int* wb = wt + ((size_t)(co*CIN + ci)*9);
        for (int kh = 0; kh < 3; ++kh) {
            int hh = h + kh - 1;
            for (int kw = 0; kw < 3; ++kw) {
                int ww2 = w + kw - 1;
                int xv = (hh >= 0 && hh < HH && ww2 >= 0 && ww2 < WW)
                         ? xb[hh*WW + ww2] : 3;
                acc += xv * wb[kh*3 + kw];
            }
        }
    }
    float sc = __fdiv_rn(__fmul_rn(0.05f, wscale[co]), 0.1f);
    float y = __fadd_rn(__fmul_rn((float)(acc + bias[co]), sc), -2.0f);
    y = rintf(y);
    y = fminf(fmaxf(y, -128.0f), 127.0f);
    out[idx] = (int)y;
}

extern "C" void kernel_launch(void* const* d_in, const int* in_sizes, int n_in,
                              void* d_out, int out_size, void* d_ws, size_t ws_size,
                              hipStream_t stream) {
    const int*   x      = (const int*)d_in[0];
    const int*   weight = (const int*)d_in[1];
    const int*   bias   = (const int*)d_in[2];
    const float* wscale = (const float*)d_in[3];
    int*         out    = (int*)d_out;

    const size_t XOFF = 320u << 10;                  // w8f region: 288KB used
    const size_t BPB  = (size_t)HP * WP * CIN;       // 430,592 B per batch

    int nchk = 0;
    if (ws_size >= XOFF + BPB) {
        size_t navail = (ws_size - XOFF) / BPB;
        nchk = navail >= 32 ? 32 : navail >= 16 ? 16 : navail >= 8 ? 8
             : navail >= 4 ? 4 : navail >= 2 ? 2 : 1;
    }

    if (nchk == 0) {
        size_t total = (size_t)NB * COUT * PIX;
        conv_direct_kernel<<<dim3((total + 255) / 256), dim3(256), 0, stream>>>(
            x, weight, bias, wscale, out);
        return;
    }

    unsigned char* ws  = (unsigned char*)d_ws;
    unsigned char* w8f = ws;
    unsigned char* xp8 = ws + XOFF;

    pack_w_kernel<<<dim3(COUT), dim3(128), 0, stream>>>(weight, w8f);
    for (int n0 = 0; n0 < NB; n0 += nchk) {
        int nc = (NB - n0 < nchk) ? (NB - n0) : nchk;
        pack_x_kernel<<<dim3(nc*HP), dim3(256), 0, stream>>>(x, xp8, n0);
        conv_kernel<<<dim3(NPT*nc), dim3(256), 0, stream>>>(w8f, xp8, bias, wscale, out, n0);
    }
}

// Round 8
// 63.723 us; speedup vs baseline: 2.6113x; 1.1586x over previous
//
#include <hip/hip_runtime.h>

// Quantized 3x3 conv, stride 1, pad 1 (pad value = input zero point 3).
// x: int32 [32][128][56][56] (values in int8 range)
// weight: int32 [256][128][3][3]
// bias: int32 [256]
// weight_scale: float [256]
// out: int32 [32][256][56][56] (quantized int8 values in int32 container)

#define NB    32
#define CIN   128
#define HH    56
#define WW    56
#define COUT  256
#define HP    58          // padded H
#define WP    58          // padded W
#define PIX   (HH*WW)     // 3136
#define KTOT  1152        // 9 * 128
#define NCHUNK 18         // K chunks of 64

#define NPT   28          // pixel tiles per batch (3136 = 28*112)
#define BN    112         // pixels per block
#define NJ    7           // B fragments per wave (112/16)
#define BBYTES (NJ*1024)  // B chunk in LDS: 112 rows x 64 B (double-buffered)

typedef int v4i __attribute__((ext_vector_type(4)));

#define GLOAD_LDS(gsrc, ldst) \
    __builtin_amdgcn_global_load_lds( \
        (const __attribute__((address_space(1))) void*)(gsrc), \
        (__attribute__((address_space(3))) void*)(ldst), 16, 0, 0)

// ---------------- Phase 1a: pack x (NCHW int32 -> padded NHWC int8) -------
// LDS-transpose version: coalesced global reads (lanes = w) AND coalesced
// global writes (lanes = contiguous dwords of the NHWC row). LDS u32 tile
// [56][33] (stride 33 dwords; 33 % 32 == 1 -> worst 2-way bank alias, free).
// Borders (hp==0/57 rows, wp==0/57 cols) are filled inline; all threads
// reach the barrier.
__global__ void pack_x_kernel(const int* __restrict__ x,
                              unsigned char* __restrict__ xp8,
                              int n0) {
    int bx = blockIdx.x;
    int nl = bx / HP;
    int hp = bx % HP;
    int nb = n0 + nl;
    int tid = threadIdx.x;         // 256
    unsigned int* rowo = (unsigned int*)(xp8 + (size_t)(nl*HP + hp) * WP * CIN);

    if (hp == 0 || hp == HP-1) {   // full pad row: 1856 dwords
        const v4i zp = {0x03030303, 0x03030303, 0x03030303, 0x03030303};
        for (int i = tid; i < (WP*CIN)/16; i += 256)
            ((v4i*)rowo)[i] = zp;
        return;
    }

    __shared__ unsigned int lt[WW * 33];   // 56 x 33 dwords = 7392 B

    int h  = hp - 1;
    int wl = tid & 63;             // lane = w (0..55 active)
    int cg = tid >> 6;             // wave index = ci phase 0..3
    if (wl < WW) {
        const int s = HH*WW;
#pragma unroll
        for (int k = 0; k < 8; ++k) {
            int ci0 = cg*4 + k*16;                     // consecutive ci0..ci0+3
            const int* xb = x + (((size_t)(nb*CIN + ci0)*HH + h)*WW + wl);
            int v0 = xb[0], v1 = xb[s], v2 = xb[2*s], v3 = xb[3*s];
            unsigned int pack = (v0 & 0xFF) | ((v1 & 0xFF) << 8) |
                                ((v2 & 0xFF) << 16) | ((unsigned)(v3 & 0xFF) << 24);
            lt[wl*33 + (ci0 >> 2)] = pack;
        }
    }
    __syncthreads();

    // stream out interior: 56 px * 32 dwords = 1792 dwords, lane-contiguous
#pragma unroll
    for (int it = 0; it < 7; ++it) {
        int idx = it*256 + tid;
        int p = idx >> 5;          // pixel 0..55
        int d = idx & 31;          // dword within pixel
        rowo[(p + 1)*32 + d] = lt[p*33 + d];
    }
    // border columns wp==0 and wp==57 (32 dwords each)
    if (tid < 64) {
        int off = (tid < 32) ? tid : ((WP-1)*32 + (tid - 32));
        rowo[off] = 0x03030303u;
    }
}

// ---------------- Phase 1b: pack weight into FRAGMENT order ----------------
// w8f[((t*16 + g)*16 + lr)*64 + (k&63)], t=k>>6 chunk, g=co>>4, lr=co&15,
// k = r*128 + ci (tap-major). A wave's A-fragment = contiguous 1KB.
__global__ void pack_w_kernel(const int* __restrict__ wt,
                              unsigned char* __restrict__ w8f) {
    int co = blockIdx.x;           // 256
    int t  = threadIdx.x;          // 128
    for (int idx = t; idx < KTOT/4; idx += 128) {
        int k  = idx * 4;
        int r  = k >> 7;           // tap 0..8
        int ci = k & 127;
        const int* wb = wt + ((co*CIN + ci)*9 + r);
        int v0 = wb[0], v1 = wb[9], v2 = wb[18], v3 = wb[27];
        unsigned int pack = (v0 & 0xFF) | ((v1 & 0xFF) << 8) |
                            ((v2 & 0xFF) << 16) | ((unsigned)(v3 & 0xFF) << 24);
        int tch = k >> 6;
        size_t dst = ((size_t)((tch*16 + (co >> 4))*16 + (co & 15)))*64 + (k & 63);
        *(unsigned int*)(w8f + dst) = pack;
    }
}

__device__ __forceinline__ int koff_of(int t) {
    int r  = t >> 1;
    int kh = (r >= 6) ? 2 : (r >= 3 ? 1 : 0);
    int kw = r - kh*3;
    return ((kh*WP + kw) << 7) + ((t & 1) << 6);
}

// ---------------- Phase 2: counted-vmcnt pipelined implicit GEMM ----------
// Grid: 28 pixel-tiles * nc batches. Block: 256 threads = 4 waves.
// Tile: 256 co x 112 px. Wave wm: co in [wm*64, wm*64+64) x all 112 px.
// A: fragment-ordered w8f -> regs (coalesced 1KB loads, double-buffered).
// B: 112px x 64B via global_load_lds w16, LDS double-buffered, XOR swizzle.
// Each wave issues 2 B-stage ops (wave 3 duplicates slot 6) + 4 A loads per
// iter -> uniform counted waits: vmcnt(10) main loop, vmcnt(4) last iter.
__launch_bounds__(256, 2)
__global__ void conv_kernel(const unsigned char* __restrict__ w8f,
                            const unsigned char* __restrict__ xp8,
                            const int* __restrict__ bias,
                            const float* __restrict__ wscale,
                            int* __restrict__ out,
                            int n0) {
    __shared__ __align__(16) unsigned char ldsB[2*BBYTES];

    int bx = blockIdx.x;
    int pt = bx % NPT;
    int nl = bx / NPT;
    int nb = n0 + nl;
    int p0 = pt * BN;

    int tid  = threadIdx.x;
    int lane = tid & 63;
    int wm   = tid >> 6;           // 0..3
    int lr   = lane & 15;
    int lg   = lane >> 4;

    // ---- B staging: slots s0,s1 per wave (16 px x 64B each) ----
    int l4 = lane >> 2;                              // row within 16-row group
    int sw = (lane & 3) ^ ((lane >> 3) & 3);         // swizzled data k-slot
    int s0 = wm*2;
    int s1 = (wm*2+1 > 6) ? 6 : wm*2+1;              // wave3 duplicates slot 6
    int s0u = __builtin_amdgcn_readfirstlane(s0);
    int s1u = __builtin_amdgcn_readfirstlane(s1);
    int pA = p0 + s0*16 + l4;
    int pB = p0 + s1*16 + l4;
    const unsigned char* bsrc0 =
        xp8 + ((size_t)((nl*HP + pA/WW)*WP + pA%WW))*CIN + sw*16;
    const unsigned char* bsrc1 =
        xp8 + ((size_t)((nl*HP + pB/WW)*WP + pB%WW))*CIN + sw*16;

    // ---- B fragment read address (swizzled) ----
    int rslot = lg ^ ((lr >> 1) & 3);
    int vb = lr*64 + rslot*16;                       // b[j] at vb + j*1024

    // ---- A fragment base: contiguous 1KB per (chunk, frag) ----
    const unsigned char* abase = w8f + (size_t)(wm*4)*1024 + (lr*64 + lg*16);

    v4i acc[4][NJ];
#pragma unroll
    for (int i = 0; i < 4; ++i)
#pragma unroll
        for (int j = 0; j < NJ; ++j)
            acc[i][j] = (v4i){0, 0, 0, 0};

#define STAGE_B(T, BUFOFF) do {                                                \
        int koff_ = koff_of(T);                                                \
        GLOAD_LDS(bsrc0 + koff_, &ldsB[(BUFOFF) + s0u*1024]);                  \
        GLOAD_LDS(bsrc1 + koff_, &ldsB[(BUFOFF) + s1u*1024]);                  \
    } while (0)

    v4i a_cur[4], a_nxt[4];
    // prologue: 2 stage ops + 4 A-loads in flight
    STAGE_B(0, 0);
#pragma unroll
    for (int i = 0; i < 4; ++i) a_cur[i] = *(const v4i*)(abase + i*1024);

#pragma unroll
    for (int t = 0; t < NCHUNK; ++t) {
        if (t < NCHUNK-1) {
            STAGE_B(t+1, ((t+1)&1)*BBYTES);
#pragma unroll
            for (int i = 0; i < 4; ++i)
                a_nxt[i] = *(const v4i*)(abase + (size_t)(t+1)*16384 + i*1024);
            // younger than own B(t): A(t)x4 + B(t+1)x2 + A(t+1)x4 = 10
            asm volatile("s_waitcnt vmcnt(10)" ::: "memory");
        } else {
            asm volatile("s_waitcnt vmcnt(4)" ::: "memory");
        }
        __builtin_amdgcn_sched_barrier(0);
        __builtin_amdgcn_s_barrier();      // all waves' B(t) visible in LDS

        v4i b_[NJ];
#pragma unroll
        for (int j = 0; j < NJ; ++j)
            b_[j] = *(const v4i*)&ldsB[(t&1)*BBYTES + vb + j*1024];
#pragma unroll
        for (int i = 0; i < 4; ++i)
#pragma unroll
            for (int j = 0; j < NJ; ++j)
                acc[i][j] = __builtin_amdgcn_mfma_i32_16x16x64_i8(
                    a_cur[i], b_[j], acc[i][j], 0, 0, 0);

        __builtin_amdgcn_s_barrier();      // all waves done reading buf[t&1]
        if (t < NCHUNK-1) {
#pragma unroll
            for (int i = 0; i < 4; ++i) a_cur[i] = a_nxt[i];
        }
    }
#undef STAGE_B

    // Epilogue: q = clamp(rint((acc+bias) * (0.05*ws/0.1) + (-2)), -128, 127)
#pragma unroll
    for (int i = 0; i < 4; ++i) {
#pragma unroll
        for (int rr = 0; rr < 4; ++rr) {
            int co = wm*64 + i*16 + lg*4 + rr;
            float sc = __fdiv_rn(__fmul_rn(0.05f, wscale[co]), 0.1f);
            int bs = bias[co];
            int* orow = out + ((size_t)(nb*COUT + co))*PIX + p0;
#pragma unroll
            for (int j = 0; j < NJ; ++j) {
                float accf = (float)(acc[i][j][rr] + bs);
                float y = __fadd_rn(__fmul_rn(accf, sc), -2.0f);
                y = rintf(y);
                y = fminf(fmaxf(y, -128.0f), 127.0f);
                orow[j*16 + lr] = (int)y;
            }
        }
    }
}

// ---------------- Fallback: naive direct conv (only if ws too small) ------
__launch_bounds__(256)
__global__ void conv_direct_kernel(const int* __restrict__ x,
                                   const int* __restrict__ wt,
                                   const int* __restrict__ bias,
                                   const float* __restrict__ wscale,
                                   int* __restrict__ out) {
    size_t idx = (size_t)blockIdx.x * 256 + threadIdx.x;
    if (idx >= (size_t)NB * COUT * PIX) return;
    int w  = idx % WW;
    int h  = (idx / WW) % HH;
    int co = (idx / PIX) % COUT;
    int nb = idx / ((size_t)PIX * COUT);
    int acc = 0;
    for (int ci = 0; ci < CIN; ++ci) {
        const int* xb = x + ((size_t)(nb*CIN + ci)*HH)*WW;
        const int* wb = wt + ((size_t)(co*CIN + ci)*9);
        for (int kh = 0; kh < 3; ++kh) {
            int hh = h + kh - 1;
            for (int kw = 0; kw < 3; ++kw) {
                int ww2 = w + kw - 1;
                int xv = (hh >= 0 && hh < HH && ww2 >= 0 && ww2 < WW)
                         ? xb[hh*WW + ww2] : 3;
                acc += xv * wb[kh*3 + kw];
            }
        }
    }
    float sc = __fdiv_rn(__fmul_rn(0.05f, wscale[co]), 0.1f);
    float y = __fadd_rn(__fmul_rn((float)(acc + bias[co]), sc), -2.0f);
    y = rintf(y);
    y = fminf(fmaxf(y, -128.0f), 127.0f);
    out[idx] = (int)y;
}

extern "C" void kernel_launch(void* const* d_in, const int* in_sizes, int n_in,
                              void* d_out, int out_size, void* d_ws, size_t ws_size,
                              hipStream_t stream) {
    const int*   x      = (const int*)d_in[0];
    const int*   weight = (const int*)d_in[1];
    const int*   bias   = (const int*)d_in[2];
    const float* wscale = (const float*)d_in[3];
    int*         out    = (int*)d_out;

    const size_t XOFF = 320u << 10;                  // w8f region: 288KB used
    const size_t BPB  = (size_t)HP * WP * CIN;       // 430,592 B per batch

    int nchk = 0;
    if (ws_size >= XOFF + BPB) {
        size_t navail = (ws_size - XOFF) / BPB;
        nchk = navail >= 32 ? 32 : navail >= 16 ? 16 : navail >= 8 ? 8
             : navail >= 4 ? 4 : navail >= 2 ? 2 : 1;
    }

    if (nchk == 0) {
        size_t total = (size_t)NB * COUT * PIX;
        conv_direct_kernel<<<dim3((total + 255) / 256), dim3(256), 0, stream>>>(
            x, weight, bias, wscale, out);
        return;
    }

    unsigned char* ws  = (unsigned char*)d_ws;
    unsigned char* w8f = ws;
    unsigned char* xp8 = ws + XOFF;

    pack_w_kernel<<<dim3(COUT), dim3(128), 0, stream>>>(weight, w8f);
    for (int n0 = 0; n0 < NB; n0 += nchk) {
        int nc = (NB - n0 < nchk) ? (NB - n0) : nchk;
        pack_x_kernel<<<dim3(nc*HP), dim3(256), 0, stream>>>(x, xp8, n0);
        conv_kernel<<<dim3(NPT*nc), dim3(256), 0, stream>>>(w8f, xp8, bias, wscale, out, n0);
    }
}